// Round 9
// baseline (499.322 us; speedup 1.0000x reference)
//
#include <hip/hip_runtime.h>

#define NCH    8
#define NBASIS 30
#define NXS    256
#define NF     200
#define NX     (NXS*NXS*2)      // 131072
#define NIMG   (NCH*NBASIS)     // 240

typedef float f32x2 __attribute__((ext_vector_type(2)));

__device__ __forceinline__ int bitrev8(int v) {
    return (int)(__builtin_bitreverse32((unsigned)v) >> 24);
}

// ---------------------------------------------------------------------------
// Pass 1: w = (x * csm) * (-1)^(row+col); FFT along the contiguous (col) axis.
// ---------------------------------------------------------------------------
__global__ __launch_bounds__(256) void fft_rows_kernel(
        const float* __restrict__ x, const float* __restrict__ csm,
        float* __restrict__ A) {
    __shared__ float ldsRe[4][256];
    __shared__ float ldsIm[4][256];
    __shared__ float twRe[128], twIm[128];

    const int tid   = threadIdx.x;
    const int slice = tid >> 6;
    const int lane  = tid & 63;
    const int blk   = blockIdx.x;       // m*64 + rowTile
    const int m     = blk >> 6;
    const int row   = ((blk & 63) << 2) + slice;
    const int c     = m / NBASIS;
    const int b     = m - c * NBASIS;

    if (tid < 128) {
        float a = (float)tid * (1.0f / 128.0f);   // theta = pi * a
        twRe[tid] =  cospif(a);
        twIm[tid] = -sinpif(a);
    }

    const float* xr = x   + ((size_t)(b * NXS + row) * NXS) * 2;
    const float* cr = csm + ((size_t)(c * NXS + row) * NXS) * 2;
    #pragma unroll
    for (int j = 0; j < 4; ++j) {
        int col = lane + 64 * j;
        float2 xv = *(const float2*)(xr + col * 2);
        float2 cv = *(const float2*)(cr + col * 2);
        float s = ((row + col) & 1) ? -1.0f : 1.0f;
        ldsRe[slice][col] = s * (xv.x * cv.x - xv.y * cv.y);
        ldsIm[slice][col] = s * (xv.x * cv.y + xv.y * cv.x);
    }
    __syncthreads();

    #pragma unroll
    for (int half = 128; half >= 1; half >>= 1) {
        #pragma unroll
        for (int qq = 0; qq < 2; ++qq) {
            int q  = lane + 64 * qq;
            int g  = q / half;
            int j  = q - g * half;
            int i0 = g * 2 * half + j;
            int i1 = i0 + half;
            float ar = ldsRe[slice][i0], ai = ldsIm[slice][i0];
            float br = ldsRe[slice][i1], bi = ldsIm[slice][i1];
            ldsRe[slice][i0] = ar + br;
            ldsIm[slice][i0] = ai + bi;
            float dr = ar - br, di = ai - bi;
            int k = j * (128 / half);
            float wr = twRe[k], wi = twIm[k];
            ldsRe[slice][i1] = dr * wr - di * wi;
            ldsIm[slice][i1] = dr * wi + di * wr;
        }
        __syncthreads();
    }

    float* outp = A + (size_t)m * (NXS * NXS * 2) + (size_t)row * NXS * 2;
    #pragma unroll
    for (int j = 0; j < 4; ++j) {
        int k  = lane + 64 * j;
        int rk = bitrev8(k);
        *(float2*)(outp + k * 2) = make_float2(ldsRe[slice][rk], ldsIm[slice][rk]);
    }
}

// ---------------------------------------------------------------------------
// Pass 2: FFT along the row axis (stride-256 columns), in place.
// ---------------------------------------------------------------------------
#define CTILE 16
__global__ __launch_bounds__(256) void fft_cols_kernel(float* __restrict__ A) {
    __shared__ float ldsRe[CTILE][257];
    __shared__ float ldsIm[CTILE][257];
    __shared__ float twRe[128], twIm[128];

    const int tid = threadIdx.x;
    const int blk = blockIdx.x;
    const int m   = blk >> 4;             // 16 tiles per image
    const int k0  = (blk & 15) * CTILE;

    if (tid < 128) {
        float a = (float)tid * (1.0f / 128.0f);
        twRe[tid] =  cospif(a);
        twIm[tid] = -sinpif(a);
    }

    float* base = A + (size_t)m * (NXS * NXS * 2);
    #pragma unroll
    for (int it = 0; it < 16; ++it) {
        int li = it * 256 + tid;
        int r  = li >> 4;
        int cc = li & 15;
        float2 v = *(const float2*)(base + ((size_t)r * NXS + k0 + cc) * 2);
        ldsRe[cc][r] = v.x;
        ldsIm[cc][r] = v.y;
    }
    __syncthreads();

    const int slice = tid >> 6;
    const int lane  = tid & 63;

    #pragma unroll
    for (int half = 128; half >= 1; half >>= 1) {
        #pragma unroll
        for (int ci = 0; ci < 4; ++ci) {
            int col = slice * 4 + ci;
            #pragma unroll
            for (int qq = 0; qq < 2; ++qq) {
                int q  = lane + 64 * qq;
                int g  = q / half;
                int j  = q - g * half;
                int i0 = g * 2 * half + j;
                int i1 = i0 + half;
                float ar = ldsRe[col][i0], ai = ldsIm[col][i0];
                float br = ldsRe[col][i1], bi = ldsIm[col][i1];
                ldsRe[col][i0] = ar + br;
                ldsIm[col][i0] = ai + bi;
                float dr = ar - br, di = ai - bi;
                int k = j * (128 / half);
                float wr = twRe[k], wi = twIm[k];
                ldsRe[col][i1] = dr * wr - di * wi;
                ldsIm[col][i1] = dr * wi + di * wr;
            }
        }
        __syncthreads();
    }

    #pragma unroll
    for (int it = 0; it < 16; ++it) {
        int li = it * 256 + tid;
        int ky = li >> 4;
        int cc = li & 15;
        int kx = k0 + cc;
        int rk = bitrev8(ky);
        float s = (((ky + kx) & 1) ? -1.0f : 1.0f) * (1.0f / 256.0f);
        *(float2*)(base + ((size_t)ky * NXS + kx) * 2) =
            make_float2(s * ldsRe[cc][rk], s * ldsIm[cc][rk]);
    }
}

// ---------------------------------------------------------------------------
// Stage 3: out[c,f,n] = mask[f,n] * sum_b Y[c,b,n] * VT[b,f]
// R8 post-mortem: still latency-bound (~365 us, VALU 35%) — VT is 24 KB vs
// 16 KB scalar L1, so every f0-iter's 120 s_loads thrash and all waves convoy
// on lgkmcnt drains. This version tiles f: grid (n-tile, f-tile=40, c). Per
// block the VT slice is 30x40x4 = 4.8 KB -> sL1-resident after warmup; Y is
// re-read once per f-tile (5x) but is 126 MB -> L3-served, HBM unchanged.
// yr[30] stays register-resident (proven R8 pattern); live set ~50 VGPR
// -> 8 waves/SIMD.
// ---------------------------------------------------------------------------
#define FTILE 40
#define FTI   4
__global__ __launch_bounds__(256) void project_mask_kernel(
        const float* __restrict__ Y, const float* __restrict__ VT,
        const void* __restrict__ maskT, float* __restrict__ out) {
    const int n     = blockIdx.x * 256 + threadIdx.x;
    const int fbase = blockIdx.y * FTILE;
    const int c     = blockIdx.z;

    // Detect mask storage: bool-as-byte vs int32 (uniform, scalar loads).
    const unsigned* mw = (const unsigned*)maskT;
    bool byteMode = false;
    #pragma unroll
    for (int i = 0; i < 32; ++i) byteMode |= (mw[i] > 1u);

    // Y column resident in 30 VGPRs (HBM on first f-tile, L3 after).
    float yr[NBASIS];
    const float* Yp = Y + (size_t)c * NBASIS * NX + n;
    #pragma unroll
    for (int b = 0; b < NBASIS; ++b) {
        yr[b] = Yp[(size_t)b * NX];
        asm volatile("" : "+v"(yr[b]));   // forbid remat/sink
    }

    const unsigned char* m8  = (const unsigned char*)maskT + (size_t)fbase * NX + n;
    const int*           m32 = (const int*)maskT + (size_t)fbase * NX + n;
    const float*         vtp = VT + fbase;
    float* outp = out + ((size_t)c * NF + fbase) * NX + n;

    // Prefetch mask for fi = 0.
    unsigned mcur[FTI];
    #pragma unroll
    for (int j = 0; j < FTI; ++j)
        mcur[j] = byteMode ? (unsigned)m8[(size_t)j * NX]
                           : (unsigned)m32[(size_t)j * NX];

    #pragma unroll 1
    for (int fi = 0; fi < FTILE; fi += FTI) {
        // Prefetch next group's mask (consumed after this FMA block).
        unsigned mnext[FTI];
        if (fi + FTI < FTILE) {
            #pragma unroll
            for (int j = 0; j < FTI; ++j)
                mnext[j] = byteMode ? (unsigned)m8[(size_t)(fi + FTI + j) * NX]
                                    : (unsigned)m32[(size_t)(fi + FTI + j) * NX];
        }

        float acc[FTI];
        #pragma unroll
        for (int j = 0; j < FTI; ++j) acc[j] = 0.0f;

        #pragma unroll
        for (int b = 0; b < NBASIS; ++b) {
            float y = yr[b];
            #pragma unroll
            for (int j = 0; j < FTI; ++j)
                acc[j] = fmaf(y, vtp[b * NF + fi + j], acc[j]);  // uniform -> SGPR
        }

        #pragma unroll
        for (int j = 0; j < FTI; ++j) {
            float o = (mcur[j] != 0u) ? acc[j] : 0.0f;
            __builtin_nontemporal_store(o, outp + (size_t)(fi + j) * NX);
        }

        #pragma unroll
        for (int j = 0; j < FTI; ++j) mcur[j] = mnext[j];
    }
}

extern "C" void kernel_launch(void* const* d_in, const int* in_sizes, int n_in,
                              void* d_out, int out_size, void* d_ws, size_t ws_size,
                              hipStream_t stream) {
    const float* x    = (const float*)d_in[0];   // (30,256,256,2) f32
    const float* csm  = (const float*)d_in[1];   // (8,256,256,2) f32
    const float* VT   = (const float*)d_in[2];   // (30,200) f32
    const void*  mask = d_in[3];                 // (200,131072) bool/int
    float* out = (float*)d_out;                  // (8,200,131072) f32
    float* A   = (float*)d_ws;                   // 240*256*256*2 f32 = 125.8 MB

    fft_rows_kernel<<<NIMG * 64, 256, 0, stream>>>(x, csm, A);
    fft_cols_kernel<<<NIMG * 16, 256, 0, stream>>>(A);
    project_mask_kernel<<<dim3(NX / 256, NF / FTILE, NCH), 256, 0, stream>>>(A, VT, mask, out);
}